// Round 5
// baseline (80944.232 us; speedup 1.0000x reference)
//
#include <hip/hip_runtime.h>
#include <hip/hip_fp16.h>

#define NB 64
#define NT 1000
#define NH 512
#define NI 32
#define NO 32
#define ALPHA 0.05f
#define NOISE_STD 0.05f

#define LROWS 96          // rows of W' in LDS
#define LDWC 52           // dwords per LDS col (48 data + 4 pad -> near conflict-free)

typedef unsigned int uint32;
typedef __attribute__((ext_vector_type(2))) _Float16 half2v;

static __device__ __forceinline__ float dot2f(uint32 a, uint32 b, float c) {
#if __has_builtin(__builtin_amdgcn_fdot2)
    return __builtin_amdgcn_fdot2(__builtin_bit_cast(half2v, a),
                                  __builtin_bit_cast(half2v, b), c, false);
#else
    half2v av = __builtin_bit_cast(half2v, a);
    half2v bv = __builtin_bit_cast(half2v, b);
    return c + (float)av[0] * (float)bv[0] + (float)av[1] * (float)bv[1];
#endif
}

static __device__ __forceinline__ uint32 pack2(float a, float b) {
    __half2 hp = __floats2half2_rn(a, b);
    return *(uint32*)&hp;
}

// One WG per batch element. Thread j owns column j: h_j, y_j = sum_i r_i W'[i][j].
// W' = (alpha/tM_j * g_j) * wrec  : rows [0,96) in LDS, rows [96,512) in VGPRs.
// No inter-WG communication; whole T-loop in one launch.
__global__ __launch_bounds__(512, 2) void rnn_single_kernel(
    const float* __restrict__ x, const float* __restrict__ noise,
    const float* __restrict__ wi, const float* __restrict__ wrec,
    const float* __restrict__ wout, const float* __restrict__ bias,
    const float* __restrict__ g, const float* __restrict__ tM,
    const float* __restrict__ h0, float* __restrict__ out)
{
    __shared__ __align__(16) uint32 wl[NH * LDWC];   // 106.5 KB: W' rows [0,96)
    __shared__ __align__(16) uint32 wi16[NH * 16];   // 32 KB: (alpha/tM)*wi, unit-swizzled
    __shared__ __align__(16) uint32 r32[NH / 2];     // 1 KB: r(t) f16 pairs
    __shared__ __align__(16) uint32 xs16[16];        // x_t f16 pairs

    const int b = blockIdx.x;
    const int j = threadIdx.x;
    const int w = j >> 6, l = j & 63;

    const float a_inv = ALPHA / tM[j];
    const float scale = a_inv * g[j];
    const float hs1 = 1.0f - a_inv;
    const float hb = a_inv * bias[j];
    float h = h0[j];

    // ---- stage W' rows [0,96) into LDS (f16 pairs), padded-52 layout ----
    #pragma unroll
    for (int u = 0; u < 48; ++u)
        wl[j * LDWC + u] = pack2(scale * wrec[(size_t)(2 * u) * NH + j],
                                 scale * wrec[(size_t)(2 * u + 1) * NH + j]);

    // ---- W' rows [96,512) into registers: 52 uint4 = 208 dwords = 416 rows ----
    uint4 wr[52];
    #pragma unroll
    for (int u = 0; u < 52; ++u) {
        const int base = LROWS + 8 * u;
        wr[u].x = pack2(scale * wrec[(size_t)(base + 0) * NH + j],
                        scale * wrec[(size_t)(base + 1) * NH + j]);
        wr[u].y = pack2(scale * wrec[(size_t)(base + 2) * NH + j],
                        scale * wrec[(size_t)(base + 3) * NH + j]);
        wr[u].z = pack2(scale * wrec[(size_t)(base + 4) * NH + j],
                        scale * wrec[(size_t)(base + 5) * NH + j]);
        wr[u].w = pack2(scale * wrec[(size_t)(base + 6) * NH + j],
                        scale * wrec[(size_t)(base + 7) * NH + j]);
    }

    // ---- (alpha/tM)*wi into LDS, 16 dwords/col, 16B-unit swizzle u^(j&3) ----
    #pragma unroll
    for (int u = 0; u < 4; ++u) {
        const int s = u ^ (j & 3);
        #pragma unroll
        for (int d = 0; d < 4; ++d) {
            const int i0 = 8 * u + 2 * d;
            wi16[j * 16 + s * 4 + d] = pack2(a_inv * wi[(size_t)i0 * NH + j],
                                             a_inv * wi[(size_t)(i0 + 1) * NH + j]);
        }
    }

    // ---- wout in registers: wave w -> cols 4w..4w+3, lane l -> rows 8l..8l+8 ----
    uint32 wor[4][4];
    #pragma unroll
    for (int c = 0; c < 4; ++c)
        #pragma unroll
        for (int u = 0; u < 4; ++u)
            wor[c][u] = pack2(wout[(size_t)(8 * l + 2 * u) * NO + 4 * w + c],
                              wout[(size_t)(8 * l + 2 * u + 1) * NO + 4 * w + c]);

    __syncthreads();

    const float* noisep = noise + (size_t)b * NT * NH + j;
    const float* xp     = x + (size_t)b * NT * NI;
    float* outp         = out + (size_t)b * NT * NO;

    for (int t = 0; t < NT; ++t) {
        // r(t) = relu(h) -> LDS (f16); stage x_t (wave 1, lanes 0..15)
        const float rv = fmaxf(h, 0.f);
        ((unsigned short*)r32)[j] = __half_as_ushort(__float2half(rv));
        if (j >= 64 && j < 80) {
            const int li = j - 64;
            xs16[li] = pack2(xp[t * NI + 2 * li], xp[t * NI + 2 * li + 1]);
        }
        __syncthreads();

        // noise prefetch (hides under the matvec)
        const float nv = noisep[(size_t)t * NH];

        // matvec: rows [0,96) from LDS weights
        float a0 = 0.f, a1 = 0.f, a2 = 0.f, a3 = 0.f;
        #pragma unroll
        for (int u = 0; u < 12; ++u) {
            const uint4 rr = *(const uint4*)(r32 + 4 * u);            // broadcast
            const uint4 ww = *(const uint4*)(wl + j * LDWC + 4 * u);
            a0 = dot2f(ww.x, rr.x, a0); a1 = dot2f(ww.y, rr.y, a1);
            a2 = dot2f(ww.z, rr.z, a2); a3 = dot2f(ww.w, rr.w, a3);
        }
        // rows [96,512) from register weights
        #pragma unroll
        for (int u = 0; u < 52; ++u) {
            const uint4 rr = *(const uint4*)(r32 + 48 + 4 * u);       // broadcast
            a0 = dot2f(wr[u].x, rr.x, a0); a1 = dot2f(wr[u].y, rr.y, a1);
            a2 = dot2f(wr[u].z, rr.z, a2); a3 = dot2f(wr[u].w, rr.w, a3);
        }
        // + (alpha/tM)*(x_t @ wi)
        #pragma unroll
        for (int u = 0; u < 4; ++u) {
            const uint4 xx = *(const uint4*)(xs16 + 4 * u);           // broadcast
            const uint4 ww = *(const uint4*)(wi16 + j * 16 + (u ^ (j & 3)) * 4);
            a0 = dot2f(ww.x, xx.x, a0); a1 = dot2f(ww.y, xx.y, a1);
            a2 = dot2f(ww.z, xx.z, a2); a3 = dot2f(ww.w, xx.w, a3);
        }
        const float acc = (a0 + a1) + (a2 + a3);

        // out-projection for row t: wave w covers cols 4w..4w+3
        {
            const uint4 rr = *(const uint4*)(r32 + 4 * l);            // lane slice, coalesced
            #pragma unroll
            for (int c = 0; c < 4; ++c) {
                float oa = dot2f(wor[c][0], rr.x, 0.f);
                oa = dot2f(wor[c][1], rr.y, oa);
                oa = dot2f(wor[c][2], rr.z, oa);
                oa = dot2f(wor[c][3], rr.w, oa);
                oa += __shfl_xor(oa, 1, 64);
                oa += __shfl_xor(oa, 2, 64);
                oa += __shfl_xor(oa, 4, 64);
                oa += __shfl_xor(oa, 8, 64);
                oa += __shfl_xor(oa, 16, 64);
                oa += __shfl_xor(oa, 32, 64);
                if (l == 0) outp[(size_t)t * NO + 4 * w + c] = oa;
            }
        }

        // h update: h <- h*(1-a) + a*b + std*noise + [a*g*(r@wrec) + a*(x@wi)]
        h = h * hs1 + hb + NOISE_STD * nv + acc;
        __syncthreads();   // protect r32/xs16 before next overwrite
    }
}

extern "C" void kernel_launch(void* const* d_in, const int* in_sizes, int n_in,
                              void* d_out, int out_size, void* d_ws, size_t ws_size,
                              hipStream_t stream) {
    const float* x     = (const float*)d_in[0];
    const float* noise = (const float*)d_in[1];
    const float* wi    = (const float*)d_in[2];
    const float* wrec  = (const float*)d_in[3];
    const float* wout  = (const float*)d_in[4];
    const float* bias  = (const float*)d_in[5];
    const float* g     = (const float*)d_in[6];
    const float* tM    = (const float*)d_in[7];
    const float* h0    = (const float*)d_in[8];
    float* out = (float*)d_out;

    rnn_single_kernel<<<NB, 512, 0, stream>>>(x, noise, wi, wrec, wout, bias,
                                              g, tM, h0, out);
}

// Round 6
// 71231.677 us; speedup vs baseline: 1.1364x; 1.1364x over previous
//
#include <hip/hip_runtime.h>
#include <hip/hip_fp16.h>

#define NB 64
#define NT 1000
#define NH 512
#define NI 32
#define NO 32
#define ALPHA 0.05f
#define NOISE_STD 0.05f

#define LDW 72            // dwords per LDS column (144 rows as f16 pairs)
#define REGU 46           // uint4 register weight units (368 rows)

typedef unsigned int uint32;
typedef __attribute__((ext_vector_type(2))) _Float16 half2v;

static __device__ __forceinline__ float dot2f(uint32 a, uint32 b, float c) {
#if __has_builtin(__builtin_amdgcn_fdot2)
    return __builtin_amdgcn_fdot2(__builtin_bit_cast(half2v, a),
                                  __builtin_bit_cast(half2v, b), c, false);
#else
    half2v av = __builtin_bit_cast(half2v, a);
    half2v bv = __builtin_bit_cast(half2v, b);
    return c + (float)av[0] * (float)bv[0] + (float)av[1] * (float)bv[1];
#endif
}

static __device__ __forceinline__ uint32 pack2(float a, float b) {
    __half2 hp = __floats2half2_rn(a, b);
    return *(uint32*)&hp;
}

// swizzled dword offset for column j, dword u (u in [0,LDW))
static __device__ __forceinline__ int wl_off(int j, int u) {
    const int U = u >> 2;
    const int P = (U < 16) ? (U ^ (j & 15)) : U;
    return j * LDW + 4 * P + (u & 3);
}

// --------- precompute c[b][t][j] = NOISE_STD*noise + (ALPHA/tM_j)*(x_t @ wi)_j  (f16) ---------
__global__ __launch_bounds__(512) void precompute_c_kernel(
    const float* __restrict__ x, const float* __restrict__ noise,
    const float* __restrict__ wi, const float* __restrict__ tM,
    __half* __restrict__ cbuf)
{
    const int bt = blockIdx.x;      // b*NT + t
    const int j = threadIdx.x;
    __shared__ float xs[NI];
    if (j < NI) xs[j] = x[(size_t)bt * NI + j];
    __syncthreads();
    const float a_inv = ALPHA * (1.0f / tM[j]);
    const float nv = noise[(size_t)bt * NH + j];
    float xw = 0.f;
    #pragma unroll
    for (int i = 0; i < NI; ++i) xw += xs[i] * wi[i * NH + j];
    cbuf[(size_t)bt * NH + j] = __float2half(NOISE_STD * nv + a_inv * xw);
}

// One WG per batch. Thread j owns column j end-to-end.
// W' = (alpha/tM_j * g_j) * wrec: rows [0,144) in LDS (swizzled), rows [144,512) in VGPRs.
// Zero inter-WG communication.
__global__ __launch_bounds__(512, 1) void rnn_single_kernel(
    const float* __restrict__ wrec, const float* __restrict__ wout,
    const float* __restrict__ bias, const float* __restrict__ g,
    const float* __restrict__ tM, const float* __restrict__ h0,
    const __half* __restrict__ cbuf, float* __restrict__ out)
{
    __shared__ __align__(16) uint32 wl[NH * LDW];    // 147 KB: W' rows [0,144)
    __shared__ __align__(16) uint32 r32[NH / 2];     // 1 KB: r(t) f16 pairs

    const int b = blockIdx.x;
    const int j = threadIdx.x;
    const int w = j >> 6, l = j & 63;

    const float a_inv = ALPHA / tM[j];
    const float scale = a_inv * g[j];
    const float hs1 = 1.0f - a_inv;
    const float hb = a_inv * bias[j];
    float h = h0[j];

    // ---- stage W' rows [0,144) into LDS, swizzled f16 pairs ----
    #pragma unroll
    for (int u = 0; u < LDW; ++u)
        wl[wl_off(j, u)] = pack2(scale * wrec[(size_t)(2 * u) * NH + j],
                                 scale * wrec[(size_t)(2 * u + 1) * NH + j]);

    // ---- W' rows [144,512) into registers: 46 uint4 = 184 dwords ----
    uint4 wr[REGU];
    #pragma unroll
    for (int u = 0; u < REGU; ++u) {
        const int base = 2 * LDW + 8 * u;
        wr[u].x = pack2(scale * wrec[(size_t)(base + 0) * NH + j],
                        scale * wrec[(size_t)(base + 1) * NH + j]);
        wr[u].y = pack2(scale * wrec[(size_t)(base + 2) * NH + j],
                        scale * wrec[(size_t)(base + 3) * NH + j]);
        wr[u].z = pack2(scale * wrec[(size_t)(base + 4) * NH + j],
                        scale * wrec[(size_t)(base + 5) * NH + j]);
        wr[u].w = pack2(scale * wrec[(size_t)(base + 6) * NH + j],
                        scale * wrec[(size_t)(base + 7) * NH + j]);
    }

    // ---- wout in registers: wave w -> cols 4w..4w+3, lane l -> rows 8l..8l+8 ----
    uint32 wor[4][4];
    #pragma unroll
    for (int c = 0; c < 4; ++c)
        #pragma unroll
        for (int u = 0; u < 4; ++u)
            wor[c][u] = pack2(wout[(size_t)(8 * l + 2 * u) * NO + 4 * w + c],
                              wout[(size_t)(8 * l + 2 * u + 1) * NO + 4 * w + c]);

    __syncthreads();

    const __half* cp = cbuf + (size_t)b * NT * NH + j;
    float* outp      = out + (size_t)b * NT * NO;

    for (int t = 0; t < NT; ++t) {
        // r(t) = relu(h) -> LDS f16
        ((unsigned short*)r32)[j] = __half_as_ushort(__float2half(fmaxf(h, 0.f)));
        __syncthreads();

        // per-step additive term (f16 cbuf; latency hides under matvec)
        const float cval = __half2float(cp[(size_t)t * NH]);

        // matvec rows [0,144) from LDS (swizzled, conflict-free b128)
        float a0 = 0.f, a1 = 0.f, a2 = 0.f, a3 = 0.f;
        #pragma unroll
        for (int U = 0; U < 18; ++U) {
            const uint4 rr = *(const uint4*)(r32 + 4 * U);              // broadcast
            const int P = (U < 16) ? (U ^ (j & 15)) : U;
            const uint4 ww = *(const uint4*)(wl + j * LDW + 4 * P);
            a0 = dot2f(ww.x, rr.x, a0); a1 = dot2f(ww.y, rr.y, a1);
            a2 = dot2f(ww.z, rr.z, a2); a3 = dot2f(ww.w, rr.w, a3);
        }
        // rows [144,512) from registers
        #pragma unroll
        for (int u = 0; u < REGU; ++u) {
            const uint4 rr = *(const uint4*)(r32 + 2 * LDW / 2 + 4 * u); // broadcast
            a0 = dot2f(wr[u].x, rr.x, a0); a1 = dot2f(wr[u].y, rr.y, a1);
            a2 = dot2f(wr[u].z, rr.z, a2); a3 = dot2f(wr[u].w, rr.w, a3);
        }
        const float acc = (a0 + a1) + (a2 + a3);

        // out-projection for row t: wave w covers cols 4w..4w+3
        {
            const uint4 rr = *(const uint4*)(r32 + 4 * l);              // coalesced
            #pragma unroll
            for (int c = 0; c < 4; ++c) {
                float oa = dot2f(wor[c][0], rr.x, 0.f);
                oa = dot2f(wor[c][1], rr.y, oa);
                oa = dot2f(wor[c][2], rr.z, oa);
                oa = dot2f(wor[c][3], rr.w, oa);
                oa += __shfl_xor(oa, 1, 64);
                oa += __shfl_xor(oa, 2, 64);
                oa += __shfl_xor(oa, 4, 64);
                oa += __shfl_xor(oa, 8, 64);
                oa += __shfl_xor(oa, 16, 64);
                oa += __shfl_xor(oa, 32, 64);
                if (l == 0) outp[(size_t)t * NO + 4 * w + c] = oa;
            }
        }

        // h <- h*(1-a) + a*b + [std*noise + a*(x@wi)] + a*g*(r@wrec)
        h = h * hs1 + hb + cval + acc;
        __syncthreads();   // protect r32 before next overwrite
    }
}

// --------- fallback (only if ws too small for cbuf) ---------
__global__ __launch_bounds__(1024, 1) void rnn_seq_kernel(
    const float* __restrict__ x, const float* __restrict__ noise,
    const float* __restrict__ wi, const float* __restrict__ wrec,
    const float* __restrict__ wout, const float* __restrict__ bias,
    const float* __restrict__ g, const float* __restrict__ tM,
    const float* __restrict__ h0, float* __restrict__ out)
{
    const int bidx = blockIdx.x;
    const int tid  = threadIdx.x;
    const int j    = tid & (NH - 1);
    const int half = tid >> 9;

    __shared__ float hs[NH];
    __shared__ float rs[NH];
    __shared__ float accb[NH];
    __shared__ float xt[NI];
    __shared__ float red[32][NO + 1];

    float a_inv = 0.f, gj = 0.f, bj = 0.f;
    if (tid < NH) {
        hs[tid] = h0[tid];
        a_inv   = ALPHA / tM[tid];
        gj      = g[tid];
        bj      = bias[tid];
    }
    __syncthreads();

    const int k   = tid & (NO - 1);
    const int seg = tid >> 5;

    for (int t = 0; t < NT; ++t) {
        if (tid < NH) rs[tid] = fmaxf(hs[tid], 0.f);
        if (t < NT - 1 && tid >= NH && tid < NH + NI)
            xt[tid - NH] = x[((size_t)bidx * NT + t) * NI + (tid - NH)];
        __syncthreads();

        float nv = 0.f;
        if (t < NT - 1 && tid < NH)
            nv = noise[((size_t)bidx * NT + t) * NH + tid];

        {
            float pp = 0.f;
            const int base = seg * 16;
            #pragma unroll
            for (int m = 0; m < 16; ++m)
                pp += rs[base + m] * wout[(base + m) * NO + k];
            red[seg][k] = pp;
        }

        float acc = 0.f;
        if (t < NT - 1) {
            const float* wrp = wrec + ((size_t)half * 256) * NH + j;
            const int rbase = half * 256;
            #pragma unroll 16
            for (int i = 0; i < 256; ++i)
                acc += rs[rbase + i] * wrp[(size_t)i * NH];
            if (half) accb[j] = acc;
        }
        __syncthreads();

        if (t < NT - 1 && tid < NH) {
            float accf = acc + accb[j];
            float xw = 0.f;
            #pragma unroll
            for (int i = 0; i < NI; ++i)
                xw += xt[i] * wi[i * NH + j];
            float hv = hs[j];
            hs[j] = hv + NOISE_STD * nv + a_inv * (-hv + gj * accf + bj + xw);
        }

        if (tid < NO) {
            float s = 0.f;
            #pragma unroll
            for (int sg = 0; sg < 32; ++sg) s += red[sg][tid];
            out[((size_t)bidx * NT + t) * NO + tid] = s;
        }
        __syncthreads();
    }
}

extern "C" void kernel_launch(void* const* d_in, const int* in_sizes, int n_in,
                              void* d_out, int out_size, void* d_ws, size_t ws_size,
                              hipStream_t stream) {
    const float* x     = (const float*)d_in[0];
    const float* noise = (const float*)d_in[1];
    const float* wi    = (const float*)d_in[2];
    const float* wrec  = (const float*)d_in[3];
    const float* wout  = (const float*)d_in[4];
    const float* bias  = (const float*)d_in[5];
    const float* g     = (const float*)d_in[6];
    const float* tM    = (const float*)d_in[7];
    const float* h0    = (const float*)d_in[8];
    float* out = (float*)d_out;

    const size_t cb_bytes = (size_t)NB * NT * NH * 2;   // 65,536,000

    if (ws_size >= cb_bytes) {
        __half* cbuf = (__half*)d_ws;
        precompute_c_kernel<<<NB * NT, 512, 0, stream>>>(x, noise, wi, tM, cbuf);
        rnn_single_kernel<<<NB, 512, 0, stream>>>(wrec, wout, bias, g, tM, h0, cbuf, out);
    } else {
        rnn_seq_kernel<<<NB, 1024, 0, stream>>>(x, noise, wi, wrec, wout, bias, g, tM, h0, out);
    }
}